// Round 6
// baseline (5388.316 us; speedup 1.0000x reference)
//
#include <hip/hip_runtime.h>
#include <hip/hip_fp16.h>
#include <cstdint>

typedef _Float16 f16x8 __attribute__((ext_vector_type(8)));
typedef float f32x4 __attribute__((ext_vector_type(4)));
typedef uint32_t u32x4 __attribute__((ext_vector_type(4)));

// B=64, T=1024, IN=256, HID=256. Gate-major columns: c = gi*256 + u.
// 16 WGs: group g = blk&7, role r = blk>>3 (blocks g and g+8 -> same XCD heuristic).
// Group g owns batches [8g, 8g+8); role r owns units [128r, 128r+128).
// Per-step h exchange through L2 in MFMA-A-fragment order.

// Workspace layout (bytes)
#define XG_OFF    0ULL
#define XG_BYTES  134217728ULL   // xg, lane-fragment order (see epilogue)
#define AP_OFF    (XG_OFF + XG_BYTES)
#define AP_BYTES  33554432ULL
#define BP_OFF    (AP_OFF + AP_BYTES)
#define BP_BYTES  524288ULL
#define WBP_OFF   (BP_OFF + BP_BYTES)
#define WBP_BYTES 524288ULL      // recurrent W as B-frags: [r][w][lane][kt][gi][i] fp16
#define BIAS_OFF  (WBP_OFF + WBP_BYTES)
#define BIAS_BYTES 4096ULL
#define HBUF_OFF  (BIAS_OFF + BIAS_BYTES)
#define HBUF_BYTES 131072ULL     // [g][rw][par][grp16][row16][8 fp16]
#define FLAG_OFF  (HBUF_OFF + HBUF_BYTES)
#define FLAG_BYTES 1024ULL       // [g][r] u32, 64B apart

#define QB(v, pat) __int_as_float(__builtin_amdgcn_ds_swizzle(__float_as_int(v), (pat)))

#define KTL(F) F(0) F(1) F(2) F(3) F(4) F(5) F(6) F(7)
#define WBL(F) F(0,0) F(0,1) F(0,2) F(0,3) F(1,0) F(1,1) F(1,2) F(1,3) \
  F(2,0) F(2,1) F(2,2) F(2,3) F(3,0) F(3,1) F(3,2) F(3,3) \
  F(4,0) F(4,1) F(4,2) F(4,3) F(5,0) F(5,1) F(5,2) F(5,3) \
  F(6,0) F(6,1) F(6,2) F(6,3) F(7,0) F(7,1) F(7,2) F(7,3)

// ---------------- Phase 0: pack weights ----------------
__global__ void pack_weights(const float* __restrict__ Wi, const float* __restrict__ Wf,
                             const float* __restrict__ Wo, const float* __restrict__ Wc,
                             const float* __restrict__ bi, const float* __restrict__ bf,
                             const float* __restrict__ bo, const float* __restrict__ bc,
                             __half* __restrict__ WBp, __half* __restrict__ Bp,
                             float* __restrict__ bias_eff)
{
    int tidg = blockIdx.x * blockDim.x + threadIdx.x;
    if (tidg < 262144) {
        // WBp[(((r*8+w)*64+l)*256) + (kt*4+gi)*8 + i] = Wh_gi[k][u]
        int i  = tidg & 7;
        int gi = (tidg >> 3) & 3;
        int kt = (tidg >> 5) & 7;
        int l  = (tidg >> 8) & 63;
        int w  = (tidg >> 14) & 7;
        int r  = (tidg >> 17) & 1;
        const float* W = (gi == 0) ? Wi : (gi == 1) ? Wf : (gi == 2) ? Wo : Wc;
        int k = 32 * kt + 8 * (l >> 4) + i;          // h-part rows [0,256)
        int u = 128 * r + 16 * w + (l & 15);
        WBp[tidg] = __float2half(W[k * 256 + u]);
    } else if (tidg < 524288) {
        // Bp for x-GEMM, gate-major cols: c = n*16+(l&15); gi=c>>8, u=c&255
        int beta = tidg - 262144;
        int i = beta & 7;
        int l = (beta >> 3) & 63;
        int kk = (beta >> 9) & 7;
        int n = beta >> 12;
        int c = n * 16 + (l & 15);
        int gi = c >> 8, u = c & 255;
        int k = kk * 32 + (l >> 4) * 8 + i;
        const float* W = (gi == 0) ? Wi : (gi == 1) ? Wf : (gi == 2) ? Wo : Wc;
        Bp[beta] = __float2half(W[(256 + k) * 256 + u]);   // x-part rows [256,512)
    } else if (tidg < 524288 + 1024) {
        int c = tidg - 524288;
        int gi = c >> 8, u = c & 255;
        const float* bb = (gi == 0) ? bi : (gi == 1) ? bf : (gi == 2) ? bo : bc;
        bias_eff[c] = bb[u];
    }
}

// ---------------- Phase 0b: pack x into A fragments ----------------
__global__ void pack_a(const float* __restrict__ x, __half* __restrict__ Ap)
{
    int t = blockIdx.x * blockDim.x + threadIdx.x;
    int l  = t & 63;
    int kk = (t >> 6) & 7;
    int m  = t >> 9;
    int row = m * 16 + (l & 15);
    int k0  = kk * 32 + (l >> 4) * 8;
    const float* src = x + (size_t)row * 256 + k0;
    f16x8 v;
#pragma unroll
    for (int i = 0; i < 8; ++i) v[i] = (_Float16)src[i];
    *reinterpret_cast<f16x8*>(Ap + (size_t)t * 8) = v;
}

// ---------------- Phase 1: xg = x @ Wx + bias, output in lstm-lane-fragment order ------
__global__ __launch_bounds__(256) void gemm_xg(const __half* __restrict__ Ap,
                                               const __half* __restrict__ Bp,
                                               const float* __restrict__ bias_eff,
                                               __half* __restrict__ xgh)
{
    int wave = threadIdx.x >> 6;
    int lane = threadIdx.x & 63;
    int mtile = blockIdx.x * 4 + wave;
    int ntbase = blockIdx.y * 16;

    f16x8 a[8];
#pragma unroll
    for (int kk = 0; kk < 8; ++kk)
        a[kk] = *reinterpret_cast<const f16x8*>(Ap + ((size_t)(mtile * 8 + kk) * 64 + lane) * 8);

    int col_lo = lane & 15;
    int rgrp = lane >> 4;
#pragma unroll 1
    for (int j = 0; j < 16; ++j) {
        int nt = ntbase + j;
        int c = nt * 16 + col_lo;
        float bb = bias_eff[c];
        f32x4 acc = {bb, bb, bb, bb};
#pragma unroll
        for (int kk = 0; kk < 8; ++kk) {
            f16x8 bfr = *reinterpret_cast<const f16x8*>(Bp + ((size_t)(nt * 8 + kk) * 64 + lane) * 8);
            acc = __builtin_amdgcn_mfma_f32_16x16x32_f16(a[kk], bfr, acc, 0, 0, 0);
        }
        int gi = c >> 8, u = c & 255;
        int rrole = u >> 7, ul = u & 127;
        int w2 = ul >> 4, cl2 = ul & 15;
#pragma unroll
        for (int r2 = 0; r2 < 4; ++r2) {
            int row = mtile * 16 + rgrp * 4 + r2;
            int b = row >> 10, t = row & 1023;
            int gg = b >> 3, bb8 = b & 7;
            int lane2 = (bb8 >> 2) * 16 + cl2;
            size_t idx = (size_t)t * 65536 +
                         (size_t)((((gg * 2 + rrole) * 8 + w2) * 32 + lane2) * 16 + gi * 4 + (bb8 & 3));
            xgh[idx] = __float2half(acc[r2]);
        }
    }
}

// ---------------- Phase 2: MFMA recurrence, 16 WGs, 2-WG groups, L2 h-exchange ---------
__global__ __launch_bounds__(512, 2) void lstm_rec(
    const __half* __restrict__ xgp,
    const __half* __restrict__ WBp,
    uint32_t* hbuf,
    uint32_t* flags,
    float* __restrict__ out)
{
    const int blk = blockIdx.x;
    const int g = blk & 7;
    const int r = blk >> 3;
    const int tid = threadIdx.x;
    const int w = tid >> 6;
    const int l = tid & 63;
    const int rg = l >> 4;
    const int cl = l & 15;
    const int ul = 16 * w + cl;

    // ---- recurrent weights as MFMA B-fragments, register-resident ----
    const __half* wp = WBp + (((size_t)(r * 8 + w) * 64 + l) << 8);
#define DECLWB(kt, gi) f16x8 wb_##kt##_##gi = *reinterpret_cast<const f16x8*>(wp + ((kt) * 4 + (gi)) * 8);
    WBL(DECLWB)
#undef DECLWB

    // A fragments (h), start at h_0 = 0
#define DECLA(kt) f16x8 a_##kt = (_Float16)0;
    KTL(DECLA)
#undef DECLA

    uint32_t* flag_self = flags + (size_t)(g * 2 + r) * 16;
    uint32_t* flag_peer = flags + (size_t)(g * 2 + (1 - r)) * 16;

    float cs0 = 0.f, cs1 = 0.f, cs2 = 0.f, cs3 = 0.f;

    union Xu { u32x4 v[2]; __half h[16]; } xu;
    const u32x4* xv = reinterpret_cast<const u32x4*>(
        xgp + (size_t)(((g * 2 + r) * 8 + w) * 32 + (l & 31)) * 16);
    xu.v[0] = xv[0]; xu.v[1] = xv[1];          // xg for t=0

    for (int t = 0; t < 1024; ++t) {
        const int parN = (t + 1) & 1;

        f32x4 acc0 = 0.f, acc1 = 0.f, acc2 = 0.f, acc3 = 0.f;
#define MF(kt) \
        acc0 = __builtin_amdgcn_mfma_f32_16x16x32_f16(a_##kt, wb_##kt##_0, acc0, 0, 0, 0); \
        acc1 = __builtin_amdgcn_mfma_f32_16x16x32_f16(a_##kt, wb_##kt##_1, acc1, 0, 0, 0); \
        acc2 = __builtin_amdgcn_mfma_f32_16x16x32_f16(a_##kt, wb_##kt##_2, acc2, 0, 0, 0); \
        acc3 = __builtin_amdgcn_mfma_f32_16x16x32_f16(a_##kt, wb_##kt##_3, acc3, 0, 0, 0);
        KTL(MF)
#undef MF

        if (l < 32) {
            uint32_t* hbW = hbuf + (size_t)((g * 2 + r) * 2 + parN) * 1024;
            float hv0, hv1, hv2, hv3;
#define ACT(rr) { \
            float pi = acc0[rr] + (float)xu.h[rr]; \
            float pf = acc1[rr] + (float)xu.h[4 + rr]; \
            float po = acc2[rr] + (float)xu.h[8 + rr]; \
            float pc = acc3[rr] + (float)xu.h[12 + rr]; \
            float ig = __builtin_amdgcn_rcpf(1.f + __builtin_amdgcn_exp2f(-1.44269504f * pi)); \
            float fg = __builtin_amdgcn_rcpf(1.f + __builtin_amdgcn_exp2f(-1.44269504f * pf)); \
            float og = __builtin_amdgcn_rcpf(1.f + __builtin_amdgcn_exp2f(-1.44269504f * po)); \
            float cg = fmaf(-2.f, __builtin_amdgcn_rcpf(1.f + __builtin_amdgcn_exp2f(2.88539008f * pc)), 1.f); \
            cs##rr = fmaf(fg, cs##rr, ig * cg); \
            float th = fmaf(-2.f, __builtin_amdgcn_rcpf(1.f + __builtin_amdgcn_exp2f(2.88539008f * cs##rr)), 1.f); \
            hv##rr = og * th; }
            ACT(0) ACT(1) ACT(2) ACT(3)
#undef ACT
            // xor-1 swizzle: even-cl lane packs (unit ul, ul+1) per batch and stores
            float p0 = QB(hv0, 0x041F), p1 = QB(hv1, 0x041F);
            float p2 = QB(hv2, 0x041F), p3 = QB(hv3, 0x041F);
            if (!(cl & 1)) {
                int base = ((ul >> 3) * 16 + 4 * rg) * 4 + ((ul & 7) >> 1);
#define STH(rr, hv, pv) hbW[base + 4 * (rr)] = \
                (uint32_t)__half_as_ushort(__float2half(hv)) | \
                ((uint32_t)__half_as_ushort(__float2half(pv)) << 16);
                STH(0, hv0, p0) STH(1, hv1, p1) STH(2, hv2, p2) STH(3, hv3, p3)
#undef STH
            }
        }

        __threadfence();
        __syncthreads();
        if (tid == 0)
            __hip_atomic_store(flag_self, (uint32_t)(t + 1), __ATOMIC_RELEASE, __HIP_MEMORY_SCOPE_AGENT);

        // out[t] = h_{t+1}: coalesced from own buffer (atomic u32 loads bypass L1)
        if (tid < 256) {
            int bb = tid >> 5;
            int u0 = (tid & 31) * 4;
            const uint32_t* hbO = hbuf + (size_t)((g * 2 + r) * 2 + parN) * 1024
                                 + ((u0 >> 3) * 16 + bb) * 4 + ((u0 >> 1) & 3);
            uint32_t q0 = __hip_atomic_load(hbO, __ATOMIC_RELAXED, __HIP_MEMORY_SCOPE_AGENT);
            uint32_t q1 = __hip_atomic_load(hbO + 1, __ATOMIC_RELAXED, __HIP_MEMORY_SCOPE_AGENT);
            f32x4 o4;
            o4[0] = __half2float(__ushort_as_half((uint16_t)(q0 & 0xffff)));
            o4[1] = __half2float(__ushort_as_half((uint16_t)(q0 >> 16)));
            o4[2] = __half2float(__ushort_as_half((uint16_t)(q1 & 0xffff)));
            o4[3] = __half2float(__ushort_as_half((uint16_t)(q1 >> 16)));
            *reinterpret_cast<f32x4*>(out + ((size_t)t * 64 + 8 * g + bb) * 256 + 128 * r + u0) = o4;
        }

        if (t < 1023) {
            if (tid == 0) {
                while (__hip_atomic_load(flag_peer, __ATOMIC_ACQUIRE, __HIP_MEMORY_SCOPE_AGENT)
                       < (uint32_t)(t + 1)) { }
            }
            __syncthreads();
            __builtin_amdgcn_fence(__ATOMIC_ACQUIRE, "agent");

            // A-fragments of h_{t+1}: uniform loads from both roles' buffers
#define LDA(kt) { \
            int rw = (kt) >> 2; \
            int grp = 4 * ((kt) & 3) + rg; \
            a_##kt = *reinterpret_cast<const f16x8*>( \
                hbuf + (size_t)((g * 2 + rw) * 2 + parN) * 1024 + (grp * 16 + cl) * 4); }
            KTL(LDA)
#undef LDA
            // xg prefetch for t+1: one t-step = 65536 halves = 8192 u32x4 (FIX: was 4096)
            xu.v[0] = xv[(size_t)(t + 1) * 8192];
            xu.v[1] = xv[(size_t)(t + 1) * 8192 + 1];
        }
    }
}

// ---------------- launch ----------------
extern "C" void kernel_launch(void* const* d_in, const int* in_sizes, int n_in,
                              void* d_out, int out_size, void* d_ws, size_t ws_size,
                              hipStream_t stream)
{
    const float* x  = (const float*)d_in[0];
    const float* Wi = (const float*)d_in[1];
    const float* bi = (const float*)d_in[2];
    const float* Wf = (const float*)d_in[3];
    const float* bf = (const float*)d_in[4];
    const float* Wo = (const float*)d_in[5];
    const float* bo = (const float*)d_in[6];
    const float* Wc = (const float*)d_in[7];
    const float* bc = (const float*)d_in[8];

    char* ws = (char*)d_ws;
    __half*   xgh      = (__half*)(ws + XG_OFF);
    __half*   Ap       = (__half*)(ws + AP_OFF);
    __half*   Bp       = (__half*)(ws + BP_OFF);
    __half*   WBp      = (__half*)(ws + WBP_OFF);
    float*    bias_eff = (float*)(ws + BIAS_OFF);
    uint32_t* hbuf     = (uint32_t*)(ws + HBUF_OFF);
    uint32_t* flags    = (uint32_t*)(ws + FLAG_OFF);

    hipMemsetAsync(flags, 0, FLAG_BYTES, stream);
    pack_weights<<<2052, 256, 0, stream>>>(Wi, Wf, Wo, Wc, bi, bf, bo, bc, WBp, Bp, bias_eff);
    pack_a<<<8192, 256, 0, stream>>>(x, Ap);
    gemm_xg<<<dim3(1024, 4), 256, 0, stream>>>(Ap, Bp, bias_eff, xgh);
    lstm_rec<<<16, 512, 0, stream>>>(xgh, WBp, hbuf, flags, (float*)d_out);
}

// Round 7
// 3014.255 us; speedup vs baseline: 1.7876x; 1.7876x over previous
//
#include <hip/hip_runtime.h>
#include <hip/hip_fp16.h>
#include <cstdint>

typedef _Float16 f16x8 __attribute__((ext_vector_type(8)));
typedef float f32x4 __attribute__((ext_vector_type(4)));
typedef int i32x4 __attribute__((ext_vector_type(4)));

// B=64, T=1024, IN=256, HID=256. Column c = 4u + gi (u=unit, gi: 0=i,1=f,2=o,3=c).
// lstm_rec: 4 WGs x 512 thr; WG g owns batches [16g,16g+16). TRANSPOSED MFMA:
// D[col][batch] = W^T(int8) . h^T(int8) via mfma_i32_16x16x64_i8 (K=64, 4 ktiles).
// Wave w owns global mtiles M=8w..8w+7 (cols 16M..16M+16). Lane: batch=l&15, and
// C-rows 4rg+r = the 4 gates of unit u = 4M+rg -> fully in-lane cell update.

#define XG_OFF    0ULL
#define XG_BYTES  134217728ULL   // xgp[t][g][w][l][mt][gi] fp16 (64B per lane per t)
#define AP_OFF    (XG_OFF + XG_BYTES)
#define AP_BYTES  33554432ULL
#define BP_OFF    (AP_OFF + AP_BYTES)
#define BP_BYTES  524288ULL
#define WAP_OFF   (BP_OFF + BP_BYTES)
#define WAP_BYTES 262144ULL      // int8 A-frags: [M][kt][l][16]
#define BIAS_OFF  (WAP_OFF + WAP_BYTES)

#define GLOROT 0.08838834764831845f
#define CSC    (GLOROT / 16129.0f)          // s_w * s_h = (g/127)*(1/127)
#define QINV   (127.0f / GLOROT)

#define EXP2(x) __builtin_amdgcn_exp2f(x)
#define RCP(x)  __builtin_amdgcn_rcpf(x)

// ---------------- Phase 0: pack weights (i8 A-frags + f16 B-frags for x-GEMM + bias) ---
__global__ void pack_weights(const float* __restrict__ Wi, const float* __restrict__ Wf,
                             const float* __restrict__ Wo, const float* __restrict__ Wc,
                             const float* __restrict__ bi, const float* __restrict__ bf,
                             const float* __restrict__ bo, const float* __restrict__ bc,
                             int8_t* __restrict__ WAp, __half* __restrict__ Bp,
                             float* __restrict__ bias_eff)
{
    int tidg = blockIdx.x * blockDim.x + threadIdx.x;
    if (tidg < 262144) {
        // WAp[((M*4+kt)*64+l)*16+i] = q(Wh_gi[k][u]), c=16M+(l&15), k=kt*64+(l>>4)*16+i
        int i  = tidg & 15;
        int l  = (tidg >> 4) & 63;
        int kt = (tidg >> 10) & 3;
        int M  = tidg >> 12;
        int c  = 16 * M + (l & 15);
        int u  = c >> 2, gi = c & 3;
        int k  = kt * 64 + (l >> 4) * 16 + i;
        const float* W = (gi == 0) ? Wi : (gi == 1) ? Wf : (gi == 2) ? Wo : Wc;
        float q = rintf(W[k * 256 + u] * QINV);       // h-part rows [0,256)
        q = fminf(127.f, fmaxf(-127.f, q));
        WAp[tidg] = (int8_t)(int)q;
    } else if (tidg < 262144 + 262144) {
        // Bp for x-GEMM: c = n*16+(l&15); u=c>>2, g=c&3; x-part rows [256,512)
        int beta = tidg - 262144;
        int i = beta & 7;
        int l = (beta >> 3) & 63;
        int kk = (beta >> 9) & 7;
        int n = beta >> 12;
        int c = n * 16 + (l & 15);
        int u = c >> 2, g = c & 3;
        int k = kk * 32 + (l >> 4) * 8 + i;
        const float* W = (g == 0) ? Wi : (g == 1) ? Wf : (g == 2) ? Wo : Wc;
        Bp[beta] = __float2half(W[(256 + k) * 256 + u]);
    } else if (tidg < 262144 + 262144 + 1024) {
        int c = tidg - 524288;
        int g = c & 3;
        const float* bb = (g == 0) ? bi : (g == 1) ? bf : (g == 2) ? bo : bc;
        bias_eff[c] = bb[c >> 2];
    }
}

// ---------------- Phase 0b: pack x into A fragments (f16 GEMM) ----------------
__global__ void pack_a(const float* __restrict__ x, __half* __restrict__ Ap)
{
    int t = blockIdx.x * blockDim.x + threadIdx.x;
    int l  = t & 63;
    int kk = (t >> 6) & 7;
    int m  = t >> 9;
    int row = m * 16 + (l & 15);
    int k0  = kk * 32 + (l >> 4) * 8;
    const float* src = x + (size_t)row * 256 + k0;
    f16x8 v;
#pragma unroll
    for (int i = 0; i < 8; ++i) v[i] = (_Float16)src[i];
    *reinterpret_cast<f16x8*>(Ap + (size_t)t * 8) = v;
}

// ---------------- Phase 1: xg = x @ Wx + bias, stored in lstm per-lane layout ----------
__global__ __launch_bounds__(256) void gemm_xg(const __half* __restrict__ Ap,
                                               const __half* __restrict__ Bp,
                                               const float* __restrict__ bias_eff,
                                               __half* __restrict__ xgh)
{
    int wave = threadIdx.x >> 6;
    int lane = threadIdx.x & 63;
    int mtile = blockIdx.x * 4 + wave;
    int ntbase = blockIdx.y * 16;

    f16x8 a[8];
#pragma unroll
    for (int kk = 0; kk < 8; ++kk)
        a[kk] = *reinterpret_cast<const f16x8*>(Ap + ((size_t)(mtile * 8 + kk) * 64 + lane) * 8);

    int col_lo = lane & 15;
    int rgrp = lane >> 4;
#pragma unroll 1
    for (int j = 0; j < 16; ++j) {
        int nt = ntbase + j;
        int c = nt * 16 + col_lo;
        float bb = bias_eff[c];
        f32x4 acc = {bb, bb, bb, bb};
#pragma unroll
        for (int kk = 0; kk < 8; ++kk) {
            f16x8 bfr = *reinterpret_cast<const f16x8*>(Bp + ((size_t)(nt * 8 + kk) * 64 + lane) * 8);
            acc = __builtin_amdgcn_mfma_f32_16x16x32_f16(a[kk], bfr, acc, 0, 0, 0);
        }
        int u = c >> 2, gi = c & 3;
        int M = u >> 2, rga = u & 3;
        int wv = M >> 3, mt = M & 7;
#pragma unroll
        for (int r2 = 0; r2 < 4; ++r2) {
            int row = mtile * 16 + rgrp * 4 + r2;
            int b = row >> 10, t = row & 1023;
            int gW = b >> 4, bl = b & 15;
            int l2 = rga * 16 + bl;
            size_t idx = ((((size_t)(t * 4 + gW) * 8 + wv) * 64 + l2) * 8 + mt) * 4 + gi;
            xgh[idx] = __float2half(acc[r2]);
        }
    }
}

// ---------------- Phase 2: recurrence, 4 independent WGs, in-WG LDS h-exchange ---------
#define KT4(F) F(0) F(1) F(2) F(3)
#define MT8(F) F(0) F(1) F(2) F(3) F(4) F(5) F(6) F(7)
#define WALL(F) F(0,0) F(0,1) F(0,2) F(0,3) F(1,0) F(1,1) F(1,2) F(1,3) \
  F(2,0) F(2,1) F(2,2) F(2,3) F(3,0) F(3,1) F(3,2) F(3,3) \
  F(4,0) F(4,1) F(4,2) F(4,3) F(5,0) F(5,1) F(5,2) F(5,3) \
  F(6,0) F(6,1) F(6,2) F(6,3) F(7,0) F(7,1) F(7,2) F(7,3)

__global__ __launch_bounds__(512, 2) void lstm_rec(
    const int8_t* __restrict__ WAp,
    const __half* __restrict__ xgp,
    float* __restrict__ out)
{
    const int g = blockIdx.x;
    const int tid = threadIdx.x;
    const int w = tid >> 6;
    const int l = tid & 63;
    const int bl = l & 15;
    const int rg = l >> 4;

    __shared__ int8_t HB[4096];   // h_q[batch 16][256 bytes, slot-XOR swizzled]

    // ---- int8 weight A-frags, register-resident (32 x i32x4 = 128 VGPRs) ----
    const i32x4* wap = reinterpret_cast<const i32x4*>(WAp);
#define DECLW(mt, kt) i32x4 wq_##mt##_##kt = wap[((w * 8 + (mt)) * 4 + (kt)) * 64 + l];
    WALL(DECLW)
#undef DECLW

    // LDS read addrs (B-frags): bl*256 + (((kt*4+rg)^bl)&15)*16
    int ra[4];
#pragma unroll
    for (int kt = 0; kt < 4; ++kt)
        ra[kt] = bl * 256 + ((((kt * 4) + rg) ^ bl) & 15) * 16;
    // LDS write addrs per mt: unit u = 32w+4mt+rg
    int wa[8];
#pragma unroll
    for (int mt = 0; mt < 8; ++mt) {
        int pos = 32 * (w & 1) + 4 * mt + rg;
        int slot = (((w >> 1) * 4 + (pos >> 4)) ^ bl) & 15;
        wa[mt] = bl * 256 + slot * 16 + (pos & 15);
    }

    i32x4 b0 = {0, 0, 0, 0}, b1 = b0, b2 = b0, b3 = b0;   // h_0 = 0
    float cs[8] = {0.f, 0.f, 0.f, 0.f, 0.f, 0.f, 0.f, 0.f};

    const __half* xp = xgp + ((size_t)(g * 8 + w) * 64 + l) * 32;
    f16x8 x0 = *reinterpret_cast<const f16x8*>(xp);
    f16x8 x1 = *reinterpret_cast<const f16x8*>(xp + 8);
    f16x8 x2 = *reinterpret_cast<const f16x8*>(xp + 16);
    f16x8 x3 = *reinterpret_cast<const f16x8*>(xp + 24);

    float* op = out + (size_t)(16 * g + bl) * 256 + 32 * w + rg;

    for (int t = 0; t < 1024; ++t) {
        int hq[8];
#define DOMT(mt, XV) { \
        i32x4 acc = {0, 0, 0, 0}; \
        acc = __builtin_amdgcn_mfma_i32_16x16x64_i8(wq_##mt##_0, b0, acc, 0, 0, 0); \
        acc = __builtin_amdgcn_mfma_i32_16x16x64_i8(wq_##mt##_1, b1, acc, 0, 0, 0); \
        acc = __builtin_amdgcn_mfma_i32_16x16x64_i8(wq_##mt##_2, b2, acc, 0, 0, 0); \
        acc = __builtin_amdgcn_mfma_i32_16x16x64_i8(wq_##mt##_3, b3, acc, 0, 0, 0); \
        float pi = fmaf((float)acc[0], CSC, (float)XV[((mt) & 1) * 4 + 0]); \
        float pf = fmaf((float)acc[1], CSC, (float)XV[((mt) & 1) * 4 + 1]); \
        float po = fmaf((float)acc[2], CSC, (float)XV[((mt) & 1) * 4 + 2]); \
        float pc = fmaf((float)acc[3], CSC, (float)XV[((mt) & 1) * 4 + 3]); \
        float ig = RCP(1.f + EXP2(-1.44269504f * pi)); \
        float fg = RCP(1.f + EXP2(-1.44269504f * pf)); \
        float og = RCP(1.f + EXP2(-1.44269504f * po)); \
        float cg = fmaf(-2.f, RCP(1.f + EXP2(2.88539008f * pc)), 1.f); \
        cs[mt] = fmaf(fg, cs[mt], ig * cg); \
        float th = fmaf(-2.f, RCP(1.f + EXP2(2.88539008f * cs[mt])), 1.f); \
        float hv = og * th; \
        op[4 * (mt)] = hv; \
        hq[mt] = (int)rintf(hv * 127.f); }

        DOMT(0, x0) DOMT(1, x0) DOMT(2, x1) DOMT(3, x1)
        DOMT(4, x2) DOMT(5, x2) DOMT(6, x3) DOMT(7, x3)
#undef DOMT

        __syncthreads();                       // all B-frag reads of h_t complete
#pragma unroll
        for (int mt = 0; mt < 8; ++mt) HB[wa[mt]] = (int8_t)hq[mt];
        __syncthreads();                       // h_{t+1} visible

        b0 = *reinterpret_cast<const i32x4*>(HB + ra[0]);
        b1 = *reinterpret_cast<const i32x4*>(HB + ra[1]);
        b2 = *reinterpret_cast<const i32x4*>(HB + ra[2]);
        b3 = *reinterpret_cast<const i32x4*>(HB + ra[3]);

        // xg prefetch for t+1 (consumed next iter; ~full-step latency window)
        const __half* xq = xp + (size_t)((t < 1023) ? (t + 1) : 1023) * 65536;
        x0 = *reinterpret_cast<const f16x8*>(xq);
        x1 = *reinterpret_cast<const f16x8*>(xq + 8);
        x2 = *reinterpret_cast<const f16x8*>(xq + 16);
        x3 = *reinterpret_cast<const f16x8*>(xq + 24);

        op += 16384;
    }
}

// ---------------- launch ----------------
extern "C" void kernel_launch(void* const* d_in, const int* in_sizes, int n_in,
                              void* d_out, int out_size, void* d_ws, size_t ws_size,
                              hipStream_t stream)
{
    const float* x  = (const float*)d_in[0];
    const float* Wi = (const float*)d_in[1];
    const float* bi = (const float*)d_in[2];
    const float* Wf = (const float*)d_in[3];
    const float* bf = (const float*)d_in[4];
    const float* Wo = (const float*)d_in[5];
    const float* bo = (const float*)d_in[6];
    const float* Wc = (const float*)d_in[7];
    const float* bc = (const float*)d_in[8];

    char* ws = (char*)d_ws;
    __half*  xgh      = (__half*)(ws + XG_OFF);
    __half*  Ap       = (__half*)(ws + AP_OFF);
    __half*  Bp       = (__half*)(ws + BP_OFF);
    int8_t*  WAp      = (int8_t*)(ws + WAP_OFF);
    float*   bias_eff = (float*)(ws + BIAS_OFF);

    pack_weights<<<2052, 256, 0, stream>>>(Wi, Wf, Wo, Wc, bi, bf, bo, bc, WAp, Bp, bias_eff);
    pack_a<<<8192, 256, 0, stream>>>(x, Ap);
    gemm_xg<<<dim3(1024, 4), 256, 0, stream>>>(Ap, Bp, bias_eff, xgh);
    lstm_rec<<<4, 512, 0, stream>>>(WAp, xgh, (float*)d_out);
}

// Round 8
// 2591.751 us; speedup vs baseline: 2.0790x; 1.1630x over previous
//
#include <hip/hip_runtime.h>
#include <hip/hip_fp16.h>
#include <cstdint>

typedef _Float16 f16x8 __attribute__((ext_vector_type(8)));
typedef float f32x4 __attribute__((ext_vector_type(4)));
typedef int i32x4 __attribute__((ext_vector_type(4)));

// B=64, T=1024, IN=256, HID=256. Column c = 4u + gi (u=unit, gi: 0=i,1=f,2=o,3=c).
// lstm_rec: 4 WGs x 512 thr; WG g owns batches [16g,16g+16). TRANSPOSED MFMA:
// D[col][batch] = W^T(int8) . h^T(int8) via mfma_i32_16x16x64_i8 (K=64, 4 ktiles).
// Wave w owns mtiles M=8w..8w+7 (cols 16M..16M+16). Lane: batch=l&15; C-rows
// 4rg+r are the 4 gates of unit u=4M+rg -> fully in-lane cell update.
// xg is PRE-SCALED per gate: i/f/o x -1.44269504, c x +2.88539008 (exp2-ready).

#define XG_OFF    0ULL
#define XG_BYTES  134217728ULL   // xgp[t][g][w][l][mt][gi] fp16 (64B per lane per t)
#define AP_OFF    (XG_OFF + XG_BYTES)
#define AP_BYTES  33554432ULL
#define BP_OFF    (AP_OFF + AP_BYTES)
#define BP_BYTES  524288ULL
#define WAP_OFF   (BP_OFF + BP_BYTES)
#define WAP_BYTES 262144ULL      // int8 A-frags: [M][kt][l][16]
#define BIAS_OFF  (WAP_OFF + WAP_BYTES)

#define GLOROT 0.08838834764831845f
#define CSC    (GLOROT / 16129.0f)            // s_w * s_h
#define CSCI   (-1.44269504f * CSC)           // sigmoid gates (pre-scaled)
#define CSCC   (2.88539008f * CSC)            // candidate gate (pre-scaled)
#define QINV   (127.0f / GLOROT)

#define EXP2(x) __builtin_amdgcn_exp2f(x)
#define RCP(x)  __builtin_amdgcn_rcpf(x)

// ---------------- Phase 0: pack weights (i8 A-frags + f16 B-frags for x-GEMM + bias) ---
__global__ void pack_weights(const float* __restrict__ Wi, const float* __restrict__ Wf,
                             const float* __restrict__ Wo, const float* __restrict__ Wc,
                             const float* __restrict__ bi, const float* __restrict__ bf,
                             const float* __restrict__ bo, const float* __restrict__ bc,
                             int8_t* __restrict__ WAp, __half* __restrict__ Bp,
                             float* __restrict__ bias_eff)
{
    int tidg = blockIdx.x * blockDim.x + threadIdx.x;
    if (tidg < 262144) {
        // WAp[((M*4+kt)*64+l)*16+i] = q(Wh_gi[k][u]), c=16M+(l&15), k=kt*64+(l>>4)*16+i
        int i  = tidg & 15;
        int l  = (tidg >> 4) & 63;
        int kt = (tidg >> 10) & 3;
        int M  = tidg >> 12;
        int c  = 16 * M + (l & 15);
        int u  = c >> 2, gi = c & 3;
        int k  = kt * 64 + (l >> 4) * 16 + i;
        const float* W = (gi == 0) ? Wi : (gi == 1) ? Wf : (gi == 2) ? Wo : Wc;
        float q = rintf(W[k * 256 + u] * QINV);       // h-part rows [0,256)
        q = fminf(127.f, fmaxf(-127.f, q));
        WAp[tidg] = (int8_t)(int)q;
    } else if (tidg < 262144 + 262144) {
        // Bp for x-GEMM: c = n*16+(l&15); u=c>>2, g=c&3; x-part rows [256,512)
        int beta = tidg - 262144;
        int i = beta & 7;
        int l = (beta >> 3) & 63;
        int kk = (beta >> 9) & 7;
        int n = beta >> 12;
        int c = n * 16 + (l & 15);
        int u = c >> 2, g = c & 3;
        int k = kk * 32 + (l >> 4) * 8 + i;
        const float* W = (g == 0) ? Wi : (g == 1) ? Wf : (g == 2) ? Wo : Wc;
        Bp[beta] = __float2half(W[(256 + k) * 256 + u]);
    } else if (tidg < 262144 + 262144 + 1024) {
        int c = tidg - 524288;
        int g = c & 3;
        const float* bb = (g == 0) ? bi : (g == 1) ? bf : (g == 2) ? bo : bc;
        bias_eff[c] = bb[c >> 2];
    }
}

// ---------------- Phase 0b: pack x into A fragments (f16 GEMM) ----------------
__global__ void pack_a(const float* __restrict__ x, __half* __restrict__ Ap)
{
    int t = blockIdx.x * blockDim.x + threadIdx.x;
    int l  = t & 63;
    int kk = (t >> 6) & 7;
    int m  = t >> 9;
    int row = m * 16 + (l & 15);
    int k0  = kk * 32 + (l >> 4) * 8;
    const float* src = x + (size_t)row * 256 + k0;
    f16x8 v;
#pragma unroll
    for (int i = 0; i < 8; ++i) v[i] = (_Float16)src[i];
    *reinterpret_cast<f16x8*>(Ap + (size_t)t * 8) = v;
}

// ---------------- Phase 1: xg = (x @ Wx + bias) * gate_scale, lstm per-lane layout -----
__global__ __launch_bounds__(256) void gemm_xg(const __half* __restrict__ Ap,
                                               const __half* __restrict__ Bp,
                                               const float* __restrict__ bias_eff,
                                               __half* __restrict__ xgh)
{
    int wave = threadIdx.x >> 6;
    int lane = threadIdx.x & 63;
    int mtile = blockIdx.x * 4 + wave;
    int ntbase = blockIdx.y * 16;

    f16x8 a[8];
#pragma unroll
    for (int kk = 0; kk < 8; ++kk)
        a[kk] = *reinterpret_cast<const f16x8*>(Ap + ((size_t)(mtile * 8 + kk) * 64 + lane) * 8);

    int col_lo = lane & 15;
    int rgrp = lane >> 4;
#pragma unroll 1
    for (int j = 0; j < 16; ++j) {
        int nt = ntbase + j;
        int c = nt * 16 + col_lo;
        float bb = bias_eff[c];
        f32x4 acc = {bb, bb, bb, bb};
#pragma unroll
        for (int kk = 0; kk < 8; ++kk) {
            f16x8 bfr = *reinterpret_cast<const f16x8*>(Bp + ((size_t)(nt * 8 + kk) * 64 + lane) * 8);
            acc = __builtin_amdgcn_mfma_f32_16x16x32_f16(a[kk], bfr, acc, 0, 0, 0);
        }
        int u = c >> 2, gi = c & 3;
        float gsc = (gi == 3) ? 2.88539008f : -1.44269504f;
        int M = u >> 2, rga = u & 3;
        int wv = M >> 3, mt = M & 7;
#pragma unroll
        for (int r2 = 0; r2 < 4; ++r2) {
            int row = mtile * 16 + rgrp * 4 + r2;
            int b = row >> 10, t = row & 1023;
            int gW = b >> 4, bl = b & 15;
            int l2 = rga * 16 + bl;
            size_t idx = ((((size_t)(t * 4 + gW) * 8 + wv) * 64 + l2) * 8 + mt) * 4 + gi;
            xgh[idx] = __float2half(acc[r2] * gsc);
        }
    }
}

// ---------------- Phase 2: recurrence, 4 WGs, 1 barrier/step, deep x prefetch ----------
#define WALL(F) F(0,0) F(0,1) F(0,2) F(0,3) F(1,0) F(1,1) F(1,2) F(1,3) \
  F(2,0) F(2,1) F(2,2) F(2,3) F(3,0) F(3,1) F(3,2) F(3,3) \
  F(4,0) F(4,1) F(4,2) F(4,3) F(5,0) F(5,1) F(5,2) F(5,3) \
  F(6,0) F(6,1) F(6,2) F(6,3) F(7,0) F(7,1) F(7,2) F(7,3)

__global__ __launch_bounds__(512, 2) void lstm_rec(
    const int8_t* __restrict__ WAp,
    const __half* __restrict__ xgp,
    float* __restrict__ out)
{
    const int g = blockIdx.x;
    const int tid = threadIdx.x;
    const int w = tid >> 6;
    const int l = tid & 63;
    const int bl = l & 15;
    const int rg = l >> 4;

    __shared__ int8_t HB[2][4096];   // h_q double-buffered: [par][batch 16][256 swizzled]

    // ---- int8 weight A-frags, register-resident (32 x i32x4, AGPR-friendly) ----
    const i32x4* wap = reinterpret_cast<const i32x4*>(WAp);
#define DECLW(mt, kt) i32x4 wq_##mt##_##kt = wap[((w * 8 + (mt)) * 4 + (kt)) * 64 + l];
    WALL(DECLW)
#undef DECLW

    // LDS read offsets (B-frags): bl*256 + (((kt*4+rg)^bl)&15)*16
    int ra[4];
#pragma unroll
    for (int kt = 0; kt < 4; ++kt)
        ra[kt] = bl * 256 + ((((kt * 4) + rg) ^ bl) & 15) * 16;
    // LDS write offsets per mt: unit pos = 32(w&1)+4mt+rg, slot XOR bl
    int wa[8];
#pragma unroll
    for (int mt = 0; mt < 8; ++mt) {
        int pos = 32 * (w & 1) + 4 * mt + rg;
        int slot = (((w >> 1) * 4 + (pos >> 4)) ^ bl) & 15;
        wa[mt] = bl * 256 + slot * 16 + (pos & 15);
    }

    i32x4 b0 = {0, 0, 0, 0}, b1 = b0, b2 = b0, b3 = b0;   // h_0 = 0
    float cs[8] = {0.f, 0.f, 0.f, 0.f, 0.f, 0.f, 0.f, 0.f};

    const __half* xp = xgp + ((size_t)(g * 8 + w) * 64 + l) * 32;
    f16x8 xA0 = *reinterpret_cast<const f16x8*>(xp);
    f16x8 xA1 = *reinterpret_cast<const f16x8*>(xp + 8);
    f16x8 xA2 = *reinterpret_cast<const f16x8*>(xp + 16);
    f16x8 xA3 = *reinterpret_cast<const f16x8*>(xp + 24);
    f16x8 xB0, xB1, xB2, xB3;

    float* op = out + (size_t)(16 * g + bl) * 256 + 32 * w + rg;

#define DOMT(mt, XV) { \
        i32x4 acc = {0, 0, 0, 0}; \
        acc = __builtin_amdgcn_mfma_i32_16x16x64_i8(wq_##mt##_0, b0, acc, 0, 0, 0); \
        acc = __builtin_amdgcn_mfma_i32_16x16x64_i8(wq_##mt##_1, b1, acc, 0, 0, 0); \
        acc = __builtin_amdgcn_mfma_i32_16x16x64_i8(wq_##mt##_2, b2, acc, 0, 0, 0); \
        acc = __builtin_amdgcn_mfma_i32_16x16x64_i8(wq_##mt##_3, b3, acc, 0, 0, 0); \
        float pi = fmaf((float)acc[0], CSCI, (float)XV[((mt) & 1) * 4 + 0]); \
        float pf = fmaf((float)acc[1], CSCI, (float)XV[((mt) & 1) * 4 + 1]); \
        float po = fmaf((float)acc[2], CSCI, (float)XV[((mt) & 1) * 4 + 2]); \
        float pc = fmaf((float)acc[3], CSCC, (float)XV[((mt) & 1) * 4 + 3]); \
        float ig = RCP(1.f + EXP2(pi)); \
        float fg = RCP(1.f + EXP2(pf)); \
        float og = RCP(1.f + EXP2(po)); \
        float cg = fmaf(-2.f, RCP(1.f + EXP2(pc)), 1.f); \
        cs[mt] = fmaf(fg, cs[mt], ig * cg); \
        float th = fmaf(-2.f, RCP(1.f + EXP2(2.88539008f * cs[mt])), 1.f); \
        float hv = og * th; \
        op[4 * (mt)] = hv; \
        hq[mt] = (int)rintf(hv * 127.f); }

    // body: prefetch x for TNEXT at top (full-step latency window), MFMA on h_t,
    // epilogue, single-buffer-parity LDS exchange with ONE barrier.
#define BODY(XC0, XC1, XC2, XC3, XN0, XN1, XN2, XN3, HBB, TNEXT) { \
        const __half* xq = xp + (size_t)(TNEXT) * 65536; \
        XN0 = *reinterpret_cast<const f16x8*>(xq); \
        XN1 = *reinterpret_cast<const f16x8*>(xq + 8); \
        XN2 = *reinterpret_cast<const f16x8*>(xq + 16); \
        XN3 = *reinterpret_cast<const f16x8*>(xq + 24); \
        int hq[8]; \
        DOMT(0, XC0) DOMT(1, XC0) DOMT(2, XC1) DOMT(3, XC1) \
        DOMT(4, XC2) DOMT(5, XC2) DOMT(6, XC3) DOMT(7, XC3) \
        _Pragma("unroll") \
        for (int mt = 0; mt < 8; ++mt) (HBB)[wa[mt]] = (int8_t)hq[mt]; \
        __syncthreads(); \
        b0 = *reinterpret_cast<const i32x4*>((HBB) + ra[0]); \
        b1 = *reinterpret_cast<const i32x4*>((HBB) + ra[1]); \
        b2 = *reinterpret_cast<const i32x4*>((HBB) + ra[2]); \
        b3 = *reinterpret_cast<const i32x4*>((HBB) + ra[3]); \
        op += 16384; }

    for (int t2 = 0; t2 < 512; ++t2) {
        int te = 2 * t2;
        BODY(xA0, xA1, xA2, xA3, xB0, xB1, xB2, xB3, HB[1], te + 1)
        int tn = (te + 2 < 1024) ? (te + 2) : 1023;
        BODY(xB0, xB1, xB2, xB3, xA0, xA1, xA2, xA3, HB[0], tn)
    }
#undef BODY
#undef DOMT
}

// ---------------- launch ----------------
extern "C" void kernel_launch(void* const* d_in, const int* in_sizes, int n_in,
                              void* d_out, int out_size, void* d_ws, size_t ws_size,
                              hipStream_t stream)
{
    const float* x  = (const float*)d_in[0];
    const float* Wi = (const float*)d_in[1];
    const float* bi = (const float*)d_in[2];
    const float* Wf = (const float*)d_in[3];
    const float* bf = (const float*)d_in[4];
    const float* Wo = (const float*)d_in[5];
    const float* bo = (const float*)d_in[6];
    const float* Wc = (const float*)d_in[7];
    const float* bc = (const float*)d_in[8];

    char* ws = (char*)d_ws;
    __half*  xgh      = (__half*)(ws + XG_OFF);
    __half*  Ap       = (__half*)(ws + AP_OFF);
    __half*  Bp       = (__half*)(ws + BP_OFF);
    int8_t*  WAp      = (int8_t*)(ws + WAP_OFF);
    float*   bias_eff = (float*)(ws + BIAS_OFF);

    pack_weights<<<2052, 256, 0, stream>>>(Wi, Wf, Wo, Wc, bi, bf, bo, bc, WAp, Bp, bias_eff);
    pack_a<<<8192, 256, 0, stream>>>(x, Ap);
    gemm_xg<<<dim3(1024, 4), 256, 0, stream>>>(Ap, Bp, bias_eff, xgh);
    lstm_rec<<<4, 512, 0, stream>>>(WAp, xgh, (float*)d_out);
}

// Round 9
// 2287.369 us; speedup vs baseline: 2.3557x; 1.1331x over previous
//
#include <hip/hip_runtime.h>
#include <hip/hip_fp16.h>
#include <cstdint>

typedef _Float16 f16x8 __attribute__((ext_vector_type(8)));
typedef float f32x4 __attribute__((ext_vector_type(4)));
typedef int i32x4 __attribute__((ext_vector_type(4)));

// B=64, T=1024, IN=256, HID=256. Column c = 4u + gi (gi: 0=i,1=f,2=o,3=c).
// lstm_rec: 4 WGs x 1024 thr (16 waves = 4/SIMD); WG g owns batches [16g,16g+16).
// TRANSPOSED MFMA: D[col][batch] = W^T(i8) . h^T(i8), mfma_i32_16x16x64_i8, 4 ktiles.
// Wave w (0..15) owns mtiles 4w..4w+3 (units 16w..16w+15). Lane: batch=l&15, rg=l>>4;
// acc[reg] for mt = gates gi=reg of unit u=16w+4mt+rg -> fully in-lane cell update.
// xg PRE-SCALED per gate: i/f/o x -1.44269504, c x +2.88539008 (exp2-ready).
// K-permutation: source-unit at k is us(k)=16(k>>4)+4(k&3)+((k>>2)&3) so the 4 rg
// lanes write 4 distinct LDS dwords (no write-side dword conflicts).

#define XG_OFF    0ULL
#define XG_BYTES  134217728ULL   // xgp[t][g][w16][l][mt4][gi4] fp16 (32B/lane/t)
#define AP_OFF    (XG_OFF + XG_BYTES)
#define AP_BYTES  33554432ULL
#define BP_OFF    (AP_OFF + AP_BYTES)
#define BP_BYTES  524288ULL
#define WAP_OFF   (BP_OFF + BP_BYTES)
#define WAP_BYTES 262144ULL      // int8 A-frags: [M64][kt4][l64][16]
#define BIAS_OFF  (WAP_OFF + WAP_BYTES)

#define GLOROT 0.08838834764831845f
#define CSC    (GLOROT / 16129.0f)            // s_w * s_h
#define CSCI   (-1.44269504f * CSC)           // sigmoid gates (pre-scaled)
#define CSCC   (2.88539008f * CSC)            // candidate gate (pre-scaled)
#define QINV   (127.0f / GLOROT)

#define EXP2(x) __builtin_amdgcn_exp2f(x)
#define RCP(x)  __builtin_amdgcn_rcpf(x)

// ---------------- Phase 0: pack weights (i8 A-frags + f16 B-frags for x-GEMM + bias) ---
__global__ void pack_weights(const float* __restrict__ Wi, const float* __restrict__ Wf,
                             const float* __restrict__ Wo, const float* __restrict__ Wc,
                             const float* __restrict__ bi, const float* __restrict__ bf,
                             const float* __restrict__ bo, const float* __restrict__ bc,
                             int8_t* __restrict__ WAp, __half* __restrict__ Bp,
                             float* __restrict__ bias_eff)
{
    int tidg = blockIdx.x * blockDim.x + threadIdx.x;
    if (tidg < 262144) {
        // WAp[((M*4+kt)*64+l)*16+i] = q(Wh_gi[us(k)][u]), c=16M+(l&15)
        int i  = tidg & 15;
        int l  = (tidg >> 4) & 63;
        int kt = (tidg >> 10) & 3;
        int M  = tidg >> 12;
        int c  = 16 * M + (l & 15);
        int u  = c >> 2, gi = c & 3;
        int khi = kt * 4 + (l >> 4);                 // k>>4
        int us  = 16 * khi + 4 * (i & 3) + (i >> 2); // permuted source unit
        const float* W = (gi == 0) ? Wi : (gi == 1) ? Wf : (gi == 2) ? Wo : Wc;
        float q = rintf(W[us * 256 + u] * QINV);     // h-part rows [0,256)
        q = fminf(127.f, fmaxf(-127.f, q));
        WAp[tidg] = (int8_t)(int)q;
    } else if (tidg < 262144 + 262144) {
        // Bp for x-GEMM: c = n*16+(l&15); u=c>>2, g=c&3; x-part rows [256,512)
        int beta = tidg - 262144;
        int i = beta & 7;
        int l = (beta >> 3) & 63;
        int kk = (beta >> 9) & 7;
        int n = beta >> 12;
        int c = n * 16 + (l & 15);
        int u = c >> 2, g = c & 3;
        int k = kk * 32 + (l >> 4) * 8 + i;
        const float* W = (g == 0) ? Wi : (g == 1) ? Wf : (g == 2) ? Wo : Wc;
        Bp[beta] = __float2half(W[(256 + k) * 256 + u]);
    } else if (tidg < 262144 + 262144 + 1024) {
        int c = tidg - 524288;
        int g = c & 3;
        const float* bb = (g == 0) ? bi : (g == 1) ? bf : (g == 2) ? bo : bc;
        bias_eff[c] = bb[c >> 2];
    }
}

// ---------------- Phase 0b: pack x into A fragments (f16 GEMM) ----------------
__global__ void pack_a(const float* __restrict__ x, __half* __restrict__ Ap)
{
    int t = blockIdx.x * blockDim.x + threadIdx.x;
    int l  = t & 63;
    int kk = (t >> 6) & 7;
    int m  = t >> 9;
    int row = m * 16 + (l & 15);
    int k0  = kk * 32 + (l >> 4) * 8;
    const float* src = x + (size_t)row * 256 + k0;
    f16x8 v;
#pragma unroll
    for (int i = 0; i < 8; ++i) v[i] = (_Float16)src[i];
    *reinterpret_cast<f16x8*>(Ap + (size_t)t * 8) = v;
}

// ---------------- Phase 1: xg = (x @ Wx + bias) * gate_scale, lstm per-lane layout -----
__global__ __launch_bounds__(256) void gemm_xg(const __half* __restrict__ Ap,
                                               const __half* __restrict__ Bp,
                                               const float* __restrict__ bias_eff,
                                               __half* __restrict__ xgh)
{
    int wave = threadIdx.x >> 6;
    int lane = threadIdx.x & 63;
    int mtile = blockIdx.x * 4 + wave;
    int ntbase = blockIdx.y * 16;

    f16x8 a[8];
#pragma unroll
    for (int kk = 0; kk < 8; ++kk)
        a[kk] = *reinterpret_cast<const f16x8*>(Ap + ((size_t)(mtile * 8 + kk) * 64 + lane) * 8);

    int col_lo = lane & 15;
    int rgrp = lane >> 4;
#pragma unroll 1
    for (int j = 0; j < 16; ++j) {
        int nt = ntbase + j;
        int c = nt * 16 + col_lo;
        float bb = bias_eff[c];
        f32x4 acc = {bb, bb, bb, bb};
#pragma unroll
        for (int kk = 0; kk < 8; ++kk) {
            f16x8 bfr = *reinterpret_cast<const f16x8*>(Bp + ((size_t)(nt * 8 + kk) * 64 + lane) * 8);
            acc = __builtin_amdgcn_mfma_f32_16x16x32_f16(a[kk], bfr, acc, 0, 0, 0);
        }
        int u = c >> 2, gi = c & 3;
        float gsc = (gi == 3) ? 2.88539008f : -1.44269504f;
        int M2 = u >> 2, rga = u & 3;
        int wv = M2 >> 2, mt = M2 & 3;
#pragma unroll
        for (int r2 = 0; r2 < 4; ++r2) {
            int row = mtile * 16 + rgrp * 4 + r2;
            int b = row >> 10, t = row & 1023;
            int gW = b >> 4, bl = b & 15;
            size_t idx = ((((size_t)(t * 4 + gW) * 16 + wv) * 64 + (rga * 16 + bl)) * 4 + mt) * 4 + gi;
            xgh[idx] = __float2half(acc[r2] * gsc);
        }
    }
}

// ---------------- Phase 2: recurrence, 4 WGs x 1024 thr, raw lgkm barrier --------------
#define WKL(F) F(0,0) F(0,1) F(0,2) F(0,3) F(1,0) F(1,1) F(1,2) F(1,3) \
  F(2,0) F(2,1) F(2,2) F(2,3) F(3,0) F(3,1) F(3,2) F(3,3)

__global__ __launch_bounds__(1024, 4) void lstm_rec(
    const int8_t* __restrict__ WAp,
    const __half* __restrict__ xgp,
    float* __restrict__ out)
{
    const int g = blockIdx.x;
    const int tid = threadIdx.x;
    const int w = tid >> 6;          // 0..15
    const int l = tid & 63;
    const int bl = l & 15;
    const int rg = l >> 4;

    __shared__ int8_t HB[2][4096];   // h_q double-buffered: [par][batch16][256 swizzled]

    // ---- int8 weight A-frags (16 x i32x4 = 64 regs, AGPR-friendly) ----
    const i32x4* wap = reinterpret_cast<const i32x4*>(WAp);
#define DECLW(mt, kt) i32x4 wq_##mt##_##kt = wap[(((4 * w + (mt)) * 4 + (kt)) * 64) + l];
    WKL(DECLW)
#undef DECLW

    // LDS read offsets (B-frags): slot = (kt*4+rg)^bl
    int ra[4];
#pragma unroll
    for (int kt = 0; kt < 4; ++kt)
        ra[kt] = bl * 256 + ((((kt * 4) + rg) ^ bl) & 15) * 16;
    // LDS write base: slot = w^bl, byte = rg*4 + mt (mt as imm offset)
    const int wab = bl * 256 + ((w ^ bl) & 15) * 16 + rg * 4;

    i32x4 b0 = {0, 0, 0, 0}, b1 = b0, b2 = b0, b3 = b0;   // h_0 = 0
    float cs_0 = 0.f, cs_1 = 0.f, cs_2 = 0.f, cs_3 = 0.f;

    const __half* xp = xgp + ((size_t)(g * 16 + w) * 64 + l) * 16;
    f16x8 xA0 = *reinterpret_cast<const f16x8*>(xp);
    f16x8 xA1 = *reinterpret_cast<const f16x8*>(xp + 8);
    f16x8 xB0, xB1;

    float* op = out + (size_t)(16 * g + bl) * 256 + 16 * w + rg;

#define DOMT(mt, XH) { \
        i32x4 acc = {0, 0, 0, 0}; \
        acc = __builtin_amdgcn_mfma_i32_16x16x64_i8(wq_##mt##_0, b0, acc, 0, 0, 0); \
        acc = __builtin_amdgcn_mfma_i32_16x16x64_i8(wq_##mt##_1, b1, acc, 0, 0, 0); \
        acc = __builtin_amdgcn_mfma_i32_16x16x64_i8(wq_##mt##_2, b2, acc, 0, 0, 0); \
        acc = __builtin_amdgcn_mfma_i32_16x16x64_i8(wq_##mt##_3, b3, acc, 0, 0, 0); \
        float pi = fmaf((float)acc[0], CSCI, (float)XH[(mt) * 4 + 0]); \
        float pf = fmaf((float)acc[1], CSCI, (float)XH[(mt) * 4 + 1]); \
        float po = fmaf((float)acc[2], CSCI, (float)XH[(mt) * 4 + 2]); \
        float pc = fminf(fmaf((float)acc[3], CSCC, (float)XH[(mt) * 4 + 3]), 60.f); \
        float Ei = EXP2(pi), Ef = EXP2(pf), Eo = EXP2(po), Ec = EXP2(pc); \
        float ic = (Ec - 1.f) * RCP((1.f + Ei) * (Ec + 1.f)); \
        float fgt = RCP(1.f + Ef); \
        cs_##mt = fmaf(fgt, cs_##mt, ic); \
        float Fm = EXP2(fminf(2.88539008f * cs_##mt, 60.f)); \
        float hv = (Fm - 1.f) * RCP((1.f + Eo) * (Fm + 1.f)); \
        op[4 * (mt)] = hv; \
        float qm = fmaf(hv, 127.f, 12582912.f); \
        HBB[wab + (mt)] = (int8_t)(__float_as_uint(qm) & 0xffu); }

#define BODY(XC, XC1, XN, XN1, PAR, TNEXT) { \
        const __half* xq = xp + (size_t)(TNEXT) * 65536; \
        XN  = *reinterpret_cast<const f16x8*>(xq); \
        XN1 = *reinterpret_cast<const f16x8*>(xq + 8); \
        int8_t* HBB = HB[PAR]; \
        union { f16x8 v[2]; __half h[16]; } xu; xu.v[0] = XC; xu.v[1] = XC1; \
        DOMT(0, xu.h) DOMT(1, xu.h) DOMT(2, xu.h) DOMT(3, xu.h) \
        asm volatile("s_waitcnt lgkmcnt(0)\n\ts_barrier" ::: "memory"); \
        b0 = *reinterpret_cast<const i32x4*>(HBB + ra[0]); \
        b1 = *reinterpret_cast<const i32x4*>(HBB + ra[1]); \
        b2 = *reinterpret_cast<const i32x4*>(HBB + ra[2]); \
        b3 = *reinterpret_cast<const i32x4*>(HBB + ra[3]); \
        op += 16384; }

    for (int t2 = 0; t2 < 512; ++t2) {
        int te = 2 * t2;
        BODY(xA0, xA1, xB0, xB1, 1, te + 1)
        int tn = (te + 2 < 1024) ? (te + 2) : 1023;
        BODY(xB0, xB1, xA0, xA1, 0, tn)
    }
#undef BODY
#undef DOMT
}

// ---------------- launch ----------------
extern "C" void kernel_launch(void* const* d_in, const int* in_sizes, int n_in,
                              void* d_out, int out_size, void* d_ws, size_t ws_size,
                              hipStream_t stream)
{
    const float* x  = (const float*)d_in[0];
    const float* Wi = (const float*)d_in[1];
    const float* bi = (const float*)d_in[2];
    const float* Wf = (const float*)d_in[3];
    const float* bf = (const float*)d_in[4];
    const float* Wo = (const float*)d_in[5];
    const float* bo = (const float*)d_in[6];
    const float* Wc = (const float*)d_in[7];
    const float* bc = (const float*)d_in[8];

    char* ws = (char*)d_ws;
    __half*  xgh      = (__half*)(ws + XG_OFF);
    __half*  Ap       = (__half*)(ws + AP_OFF);
    __half*  Bp       = (__half*)(ws + BP_OFF);
    int8_t*  WAp      = (int8_t*)(ws + WAP_OFF);
    float*   bias_eff = (float*)(ws + BIAS_OFF);

    pack_weights<<<2052, 256, 0, stream>>>(Wi, Wf, Wo, Wc, bi, bf, bo, bc, WAp, Bp, bias_eff);
    pack_a<<<8192, 256, 0, stream>>>(x, Ap);
    gemm_xg<<<dim3(1024, 4), 256, 0, stream>>>(Ap, Bp, bias_eff, xgh);
    lstm_rec<<<4, 1024, 0, stream>>>(WAp, xgh, (float*)d_out);
}